// Round 6
// baseline (224.464 us; speedup 1.0000x reference)
//
#include <hip/hip_runtime.h>
#include <cstddef>

#define B_  64
#define T_  2000
#define A_  256
#define K_  31
#define F_  32
#define TT_ 128   // t-rows per block (4 waves x 32 rows)
#define RW_ 8     // rows per inner iteration (8-way W2 reuse per LDS read)

typedef float v2f __attribute__((ext_vector_type(2)));

// tanh(x) = 1 - 2/(exp(2x)+1); saturates correctly for |x| large (rcp(inf)=0)
__device__ __forceinline__ float fast_tanh(float x) {
  float p = __expf(x + x);
  float r = __builtin_amdgcn_rcpf(p + 1.0f);
  return fmaf(-2.0f, r, 1.0f);
}

__device__ __forceinline__ float4 ld4(const float* p) {
  return *(const float4*)p;
}

// force a wave-uniform float into an SGPR (value identical across lanes)
__device__ __forceinline__ float rfl(float x) {
  return __int_as_float(__builtin_amdgcn_readfirstlane(__float_as_int(x)));
}

// Fold conv_w*loc_w -> W2[k][a]; fold query+score_b+conv_b*loc_w -> qb[b][a]
__global__ __launch_bounds__(256) void prep_kernel(
    const float* __restrict__ conv_w, const float* __restrict__ conv_b,
    const float* __restrict__ loc_w, const float* __restrict__ query,
    const float* __restrict__ score_b, float* __restrict__ W2,
    float* __restrict__ qb) {
  const int a = threadIdx.x;
  const int blk = blockIdx.x;
  if (blk < K_) {
    float acc = 0.f;
    #pragma unroll
    for (int f = 0; f < F_; ++f) acc = fmaf(conv_w[blk * F_ + f], loc_w[f * A_ + a], acc);
    W2[blk * A_ + a] = acc;
  } else {
    const int b = blk - K_;
    float acc = 0.f;
    #pragma unroll
    for (int f = 0; f < F_; ++f) acc = fmaf(conv_b[f], loc_w[f * A_ + a], acc);
    qb[b * A_ + a] = query[b * A_ + a] + score_b[a] + acc;
  }
}

// energy[b][t] = sum_a v[a] * tanh( wmem[b][t][a] + qb[b][a] + sum_k pw[b][t+k-15]*W2[k][a] )
//
// R5 lesson: VALU issue (496 scalar pl-FMAs/4 rows) ~39us and LDS pipe
// (31 w2k b128 re-reads per 4 rows) ~25us co-dominate. Here: 8 rows/iter
// (W2 LDS traffic per row halved) + float2 packed FMA (v_pk_fma_f32 halves
// pl issue). Loads issued at iter top are consumed ~1000cyc later -> latency
// covered without a prefetch double-buffer (saves 32 VGPRs).
__global__ __attribute__((amdgpu_flat_work_group_size(256, 256),
                          amdgpu_waves_per_eu(2, 4)))
void energy_kernel(
    const float* __restrict__ wmem, const float* __restrict__ pw,
    const float* __restrict__ qb, const float* __restrict__ W2,
    const float* __restrict__ score_v, float* __restrict__ energy) {
  const int b = blockIdx.y;
  const int t0 = blockIdx.x * TT_;
  const int tid = threadIdx.x;
  const int lane = tid & 63;
  const int wv = tid >> 6;

  __shared__ __align__(16) float lds_W2[K_ * A_];   // 31*256*4 = 31744B
  __shared__ __align__(16) float lds_pw[TT_ + 40];

  // stage W2 into LDS (coalesced float4)
  for (int idx = tid * 4; idx < K_ * A_; idx += 256 * 4)
    *(float4*)&lds_W2[idx] = ld4(W2 + idx);

  // stage the pw slice for this tile (index 0 == t0-15), zero-padded (SAME conv)
  if (tid < TT_ + 40) {
    const int g = t0 - 15 + tid;
    lds_pw[tid] = (g >= 0 && g < T_) ? pw[b * T_ + g] : 0.f;
  }
  __syncthreads();

  const float4 qb4 = ld4(qb + b * A_ + 4 * lane);
  const float4 v4  = ld4(score_v + 4 * lane);
  const float* wrow = wmem + (size_t)b * T_ * A_ + 4 * lane;
  const float* w2l  = lds_W2 + 4 * lane;

  const int rbase = 32 * wv;  // this wave's first row within the tile

  #pragma unroll 1
  for (int i = 0; i < 32 / RW_; ++i) {
    const int widx = rbase + RW_ * i;  // 8-aligned -> b128-aligned LDS reads

    // 8 rows of wmem; issued here, first consumed after the ~1000cyc pl loop
    float4 w4[RW_];
    #pragma unroll
    for (int j = 0; j < RW_; ++j) {
      const int t = t0 + widx + j;
      const int tc = t < T_ ? t : T_ - 1;  // wave-uniform clamp (scalar select)
      w4[j] = ld4(wrow + (size_t)tc * A_);
    }

    // pw window for rows widx..widx+7 (taps 0..30 -> 38 used) -> SGPRs
    float s[40];
    #pragma unroll
    for (int m = 0; m < 10; ++m) {
      const float4 t4 = ld4(&lds_pw[widx + 4 * m]);
      s[4 * m + 0] = rfl(t4.x); s[4 * m + 1] = rfl(t4.y);
      s[4 * m + 2] = rfl(t4.z); s[4 * m + 3] = rfl(t4.w);
    }

    // pl[j] = sum_k s[j+k] * W2[k][a4]; packed fp32 (v_pk_fma_f32), and each
    // w2k LDS read now feeds 8 rows (vs 4 in R5).
    v2f pl0[RW_], pl1[RW_];
    #pragma unroll
    for (int j = 0; j < RW_; ++j) { pl0[j] = (v2f)0.f; pl1[j] = (v2f)0.f; }
    #pragma unroll
    for (int k = 0; k < K_; ++k) {
      const float4 w2k = ld4(w2l + k * A_);
      const v2f wa = {w2k.x, w2k.y};
      const v2f wb = {w2k.z, w2k.w};
      #pragma unroll
      for (int j = 0; j < RW_; ++j) {
        const v2f sv = {s[j + k], s[j + k]};
        pl0[j] = __builtin_elementwise_fma(sv, wa, pl0[j]);
        pl1[j] = __builtin_elementwise_fma(sv, wb, pl1[j]);
      }
    }

    // per-lane partial energies for the 8 rows (no exec-mask changes here)
    float e[RW_];
    #pragma unroll
    for (int j = 0; j < RW_; ++j) {
      const float tx = fast_tanh(w4[j].x + qb4.x + pl0[j].x);
      const float ty = fast_tanh(w4[j].y + qb4.y + pl0[j].y);
      const float tz = fast_tanh(w4[j].z + qb4.z + pl1[j].x);
      const float tw = fast_tanh(w4[j].w + qb4.w + pl1[j].y);
      e[j] = fmaf(v4.x, tx, fmaf(v4.y, ty, fmaf(v4.z, tz, v4.w * tw)));
    }

    // interleaved 8-row multi-reduce: xor32+sel, xor16+sel, xor8+sel, then
    // xor4/2/1. After this, 8-lane group g = lane>>3 holds row widx+g.
    float m0 = e[0] + __shfl_xor(e[0], 32);
    float m1 = e[1] + __shfl_xor(e[1], 32);
    float m2 = e[2] + __shfl_xor(e[2], 32);
    float m3 = e[3] + __shfl_xor(e[3], 32);
    float m4 = e[4] + __shfl_xor(e[4], 32);
    float m5 = e[5] + __shfl_xor(e[5], 32);
    float m6 = e[6] + __shfl_xor(e[6], 32);
    float m7 = e[7] + __shfl_xor(e[7], 32);
    const bool b5 = (lane & 32) != 0;
    float u0 = b5 ? m4 : m0;
    float u1 = b5 ? m5 : m1;
    float u2 = b5 ? m6 : m2;
    float u3 = b5 ? m7 : m3;
    u0 += __shfl_xor(u0, 16);
    u1 += __shfl_xor(u1, 16);
    u2 += __shfl_xor(u2, 16);
    u3 += __shfl_xor(u3, 16);
    const bool b4 = (lane & 16) != 0;
    float w0 = b4 ? u2 : u0;
    float w1 = b4 ? u3 : u1;
    w0 += __shfl_xor(w0, 8);
    w1 += __shfl_xor(w1, 8);
    float y = (lane & 8) ? w1 : w0;
    y += __shfl_xor(y, 4);
    y += __shfl_xor(y, 2);
    y += __shfl_xor(y, 1);

    const int tr = t0 + widx + (lane >> 3);
    if ((lane & 7) == 0 && tr < T_) energy[b * T_ + tr] = y;
  }
}

// masked softmax over t + cumulative update; one block per batch row
__global__ __launch_bounds__(256) void softmax_kernel(
    const float* __restrict__ energy, const float* __restrict__ pw,
    const int* __restrict__ lens, float* __restrict__ out) {
  const int b = blockIdx.x;
  const int tid = threadIdx.x;
  const int len = lens[b];
  __shared__ float red[4];
  const float L2E = 1.4426950408889634f;

  // pass 1: max over valid t
  float mx = -3.4e38f;
  for (int t = tid; t < T_; t += 256)
    if (t < len) mx = fmaxf(mx, energy[b * T_ + t]);
  #pragma unroll
  for (int m = 1; m < 64; m <<= 1) mx = fmaxf(mx, __shfl_xor(mx, m, 64));
  if ((tid & 63) == 0) red[tid >> 6] = mx;
  __syncthreads();
  mx = fmaxf(fmaxf(red[0], red[1]), fmaxf(red[2], red[3]));
  __syncthreads();

  // pass 2: sum of exp
  float sm = 0.f;
  for (int t = tid; t < T_; t += 256)
    if (t < len) sm += __builtin_amdgcn_exp2f((energy[b * T_ + t] - mx) * L2E);
  #pragma unroll
  for (int m = 1; m < 64; m <<= 1) sm += __shfl_xor(sm, m, 64);
  if ((tid & 63) == 0) red[tid >> 6] = sm;
  __syncthreads();
  sm = red[0] + red[1] + red[2] + red[3];
  const float inv = 1.0f / sm;

  // pass 3: write output and new_weights
  for (int t = tid; t < T_; t += 256) {
    float o = 0.f;
    if (t < len)
      o = __builtin_amdgcn_exp2f((energy[b * T_ + t] - mx) * L2E) * inv;
    out[b * T_ + t] = o;
    out[B_ * T_ + b * T_ + t] = o + pw[b * T_ + t];
  }
}

extern "C" void kernel_launch(void* const* d_in, const int* in_sizes, int n_in,
                              void* d_out, int out_size, void* d_ws, size_t ws_size,
                              hipStream_t stream) {
  const float* query  = (const float*)d_in[0];
  const float* prev   = (const float*)d_in[1];
  const float* wmem   = (const float*)d_in[2];
  const int*   lens   = (const int*)d_in[3];
  const float* conv_w = (const float*)d_in[4];
  const float* conv_b = (const float*)d_in[5];
  const float* loc_w  = (const float*)d_in[6];
  const float* sv     = (const float*)d_in[7];
  const float* sb     = (const float*)d_in[8];
  float* out = (float*)d_out;
  float* ws  = (float*)d_ws;

  float* W2     = ws;                      // 31*256
  float* qb     = ws + K_ * A_;            // 64*256
  float* energy = ws + K_ * A_ + B_ * A_;  // 64*2000

  prep_kernel<<<K_ + B_, 256, 0, stream>>>(conv_w, conv_b, loc_w, query, sb, W2, qb);

  dim3 grid((T_ + TT_ - 1) / TT_, B_);  // 16 x 64
  energy_kernel<<<grid, 256, 0, stream>>>(wmem, prev, qb, W2, sv, energy);

  softmax_kernel<<<B_, 256, 0, stream>>>(energy, prev, lens, out);
}

// Round 7
// 216.146 us; speedup vs baseline: 1.0385x; 1.0385x over previous
//
#include <hip/hip_runtime.h>
#include <cstddef>

#define B_  64
#define T_  2000
#define A_  256
#define K_  31
#define F_  32
#define TT_ 64    // t-rows per block (2 wave-pairs x 32 rows)
#define RW_ 8     // rows per inner iteration

typedef float v2f __attribute__((ext_vector_type(2)));

// tanh(x) = 1 - 2/(exp(2x)+1); saturates correctly for |x| large (rcp(inf)=0)
__device__ __forceinline__ float fast_tanh(float x) {
  float p = __expf(x + x);
  float r = __builtin_amdgcn_rcpf(p + 1.0f);
  return fmaf(-2.0f, r, 1.0f);
}

__device__ __forceinline__ float4 ld4(const float* p) { return *(const float4*)p; }
__device__ __forceinline__ float2 ld2(const float* p) { return *(const float2*)p; }

// force a wave-uniform float into an SGPR (value identical across lanes)
__device__ __forceinline__ float rfl(float x) {
  return __int_as_float(__builtin_amdgcn_readfirstlane(__float_as_int(x)));
}

// Fold conv_w*loc_w -> W2[k][a]; fold query+score_b+conv_b*loc_w -> qb[b][a]
__global__ __launch_bounds__(256) void prep_kernel(
    const float* __restrict__ conv_w, const float* __restrict__ conv_b,
    const float* __restrict__ loc_w, const float* __restrict__ query,
    const float* __restrict__ score_b, float* __restrict__ W2,
    float* __restrict__ qb) {
  const int a = threadIdx.x;
  const int blk = blockIdx.x;
  if (blk < K_) {
    float acc = 0.f;
    #pragma unroll
    for (int f = 0; f < F_; ++f) acc = fmaf(conv_w[blk * F_ + f], loc_w[f * A_ + a], acc);
    W2[blk * A_ + a] = acc;
  } else {
    const int b = blk - K_;
    float acc = 0.f;
    #pragma unroll
    for (int f = 0; f < F_; ++f) acc = fmaf(conv_b[f], loc_w[f * A_ + a], acc);
    qb[b * A_ + a] = query[b * A_ + a] + score_b[a] + acc;
  }
}

// energy[b][t] = sum_a v[a] * tanh( wmem[b][t][a] + qb[b][a] + sum_k pw[b][t+k-15]*W2[k][a] )
//
// R6 lesson: W2-in-LDS structure plateaued at ~64us (per-block 31KB staging,
// 31 b128 w2k re-reads/8 rows, 4-float/lane footprint). Here: lane owns TWO
// a-columns -> W2 slice = 31 x float2 = 62 VGPRs, RESIDENT. A row is covered
// by a wave PAIR (cols 0-127 / 128-255); halves combine via LDS with a single
// __syncthreads per block. No W2 LDS traffic at all; pl is pure pk-fma from
// registers. amdgpu_waves_per_eu(4,4): exact 128-VGPR target (R3 drifted to
// 64+spills with a loose min; R1 got 96+rematerialize with none).
__global__ __attribute__((amdgpu_flat_work_group_size(256, 256),
                          amdgpu_waves_per_eu(4, 4)))
void energy_kernel(
    const float* __restrict__ wmem, const float* __restrict__ pw,
    const float* __restrict__ qb, const float* __restrict__ W2,
    const float* __restrict__ score_v, float* __restrict__ energy) {
  const int b = blockIdx.y;
  const int t0 = blockIdx.x * TT_;
  const int tid = threadIdx.x;
  const int lane = tid & 63;
  const int wv = tid >> 6;          // 4 waves: pairs (0,1) and (2,3)
  const int half = wv & 1;          // which 128-column half of a
  const int c0 = half * 128 + 2 * lane;  // this lane's first a-column

  __shared__ __align__(16) float lds_pw[TT_ + 40];  // taps t0-15 .. t0+63+15
  __shared__ float lds_half[2 * TT_];               // row half-sums

  // stage the pw slice (index 0 == t0-15), zero-padded (SAME conv)
  if (tid < TT_ + 40) {
    const int g = t0 - 15 + tid;
    lds_pw[tid] = (g >= 0 && g < T_) ? pw[b * T_ + g] : 0.f;
  }
  __syncthreads();

  // W2 column slice in registers: 31 x float2 = 62 VGPRs (L1/L2-hot loads)
  v2f w2r[K_];
  #pragma unroll
  for (int k = 0; k < K_; ++k) {
    const float2 w = ld2(W2 + k * A_ + c0);
    w2r[k] = (v2f){w.x, w.y};
  }
  const float2 qb2 = ld2(qb + b * A_ + c0);
  const float2 v2  = ld2(score_v + c0);
  const float* wrow = wmem + (size_t)b * T_ * A_ + c0;

  const int rbase = 32 * (wv >> 1);  // this wave-pair's first row in the tile

  #pragma unroll 1
  for (int i = 0; i < 32 / RW_; ++i) {
    const int widx = rbase + RW_ * i;  // 8-aligned

    // 8 rows of wmem, 8B/lane (512B/wave, coalesced); consumed after pl loop
    float2 w4[RW_];
    #pragma unroll
    for (int j = 0; j < RW_; ++j) {
      const int t = t0 + widx + j;
      const int tc = t < T_ ? t : T_ - 1;  // wave-uniform clamp
      w4[j] = ld2(wrow + (size_t)tc * A_);
    }

    // pw window for rows widx..widx+7 (taps 0..30 -> 38 used) -> SGPRs
    float s[40];
    #pragma unroll
    for (int m = 0; m < 10; ++m) {
      const float4 t4 = ld4(&lds_pw[widx + 4 * m]);
      s[4 * m + 0] = rfl(t4.x); s[4 * m + 1] = rfl(t4.y);
      s[4 * m + 2] = rfl(t4.z); s[4 * m + 3] = rfl(t4.w);
    }

    // pl[j] = sum_k s[j+k] * W2[k][c0..c0+1]  -- all-register pk-fma
    v2f pl[RW_];
    #pragma unroll
    for (int j = 0; j < RW_; ++j) pl[j] = (v2f)0.f;
    #pragma unroll
    for (int k = 0; k < K_; ++k) {
      #pragma unroll
      for (int j = 0; j < RW_; ++j) {
        const v2f sv = {s[j + k], s[j + k]};
        pl[j] = __builtin_elementwise_fma(sv, w2r[k], pl[j]);
      }
    }

    // per-lane partial energies (2 columns) for the 8 rows
    float e[RW_];
    #pragma unroll
    for (int j = 0; j < RW_; ++j) {
      const float tx = fast_tanh(w4[j].x + qb2.x + pl[j].x);
      const float ty = fast_tanh(w4[j].y + qb2.y + pl[j].y);
      e[j] = fmaf(v2.x, tx, v2.y * ty);
    }

    // interleaved 8-row multi-reduce over the wave's 64 lanes;
    // 8-lane group g = lane>>3 ends with the half-sum of row widx+g.
    float m0 = e[0] + __shfl_xor(e[0], 32);
    float m1 = e[1] + __shfl_xor(e[1], 32);
    float m2 = e[2] + __shfl_xor(e[2], 32);
    float m3 = e[3] + __shfl_xor(e[3], 32);
    float m4 = e[4] + __shfl_xor(e[4], 32);
    float m5 = e[5] + __shfl_xor(e[5], 32);
    float m6 = e[6] + __shfl_xor(e[6], 32);
    float m7 = e[7] + __shfl_xor(e[7], 32);
    const bool b5 = (lane & 32) != 0;
    float u0 = b5 ? m4 : m0;
    float u1 = b5 ? m5 : m1;
    float u2 = b5 ? m6 : m2;
    float u3 = b5 ? m7 : m3;
    u0 += __shfl_xor(u0, 16);
    u1 += __shfl_xor(u1, 16);
    u2 += __shfl_xor(u2, 16);
    u3 += __shfl_xor(u3, 16);
    const bool b4 = (lane & 16) != 0;
    float w0 = b4 ? u2 : u0;
    float w1 = b4 ? u3 : u1;
    w0 += __shfl_xor(w0, 8);
    w1 += __shfl_xor(w1, 8);
    float y = (lane & 8) ? w1 : w0;
    y += __shfl_xor(y, 4);
    y += __shfl_xor(y, 2);
    y += __shfl_xor(y, 1);

    if ((lane & 7) == 0)
      lds_half[half * TT_ + widx + (lane >> 3)] = y;
  }

  __syncthreads();  // the block's only post-stage barrier

  if (tid < TT_) {
    const int t = t0 + tid;
    if (t < T_)
      energy[b * T_ + t] = lds_half[tid] + lds_half[TT_ + tid];
  }
}

// masked softmax over t + cumulative update; one block per batch row
__global__ __launch_bounds__(256) void softmax_kernel(
    const float* __restrict__ energy, const float* __restrict__ pw,
    const int* __restrict__ lens, float* __restrict__ out) {
  const int b = blockIdx.x;
  const int tid = threadIdx.x;
  const int len = lens[b];
  __shared__ float red[4];
  const float L2E = 1.4426950408889634f;

  // pass 1: max over valid t
  float mx = -3.4e38f;
  for (int t = tid; t < T_; t += 256)
    if (t < len) mx = fmaxf(mx, energy[b * T_ + t]);
  #pragma unroll
  for (int m = 1; m < 64; m <<= 1) mx = fmaxf(mx, __shfl_xor(mx, m, 64));
  if ((tid & 63) == 0) red[tid >> 6] = mx;
  __syncthreads();
  mx = fmaxf(fmaxf(red[0], red[1]), fmaxf(red[2], red[3]));
  __syncthreads();

  // pass 2: sum of exp
  float sm = 0.f;
  for (int t = tid; t < T_; t += 256)
    if (t < len) sm += __builtin_amdgcn_exp2f((energy[b * T_ + t] - mx) * L2E);
  #pragma unroll
  for (int m = 1; m < 64; m <<= 1) sm += __shfl_xor(sm, m, 64);
  if ((tid & 63) == 0) red[tid >> 6] = sm;
  __syncthreads();
  sm = red[0] + red[1] + red[2] + red[3];
  const float inv = 1.0f / sm;

  // pass 3: write output and new_weights
  for (int t = tid; t < T_; t += 256) {
    float o = 0.f;
    if (t < len)
      o = __builtin_amdgcn_exp2f((energy[b * T_ + t] - mx) * L2E) * inv;
    out[b * T_ + t] = o;
    out[B_ * T_ + b * T_ + t] = o + pw[b * T_ + t];
  }
}

extern "C" void kernel_launch(void* const* d_in, const int* in_sizes, int n_in,
                              void* d_out, int out_size, void* d_ws, size_t ws_size,
                              hipStream_t stream) {
  const float* query  = (const float*)d_in[0];
  const float* prev   = (const float*)d_in[1];
  const float* wmem   = (const float*)d_in[2];
  const int*   lens   = (const int*)d_in[3];
  const float* conv_w = (const float*)d_in[4];
  const float* conv_b = (const float*)d_in[5];
  const float* loc_w  = (const float*)d_in[6];
  const float* sv     = (const float*)d_in[7];
  const float* sb     = (const float*)d_in[8];
  float* out = (float*)d_out;
  float* ws  = (float*)d_ws;

  float* W2     = ws;                      // 31*256
  float* qb     = ws + K_ * A_;            // 64*256
  float* energy = ws + K_ * A_ + B_ * A_;  // 64*2000

  prep_kernel<<<K_ + B_, 256, 0, stream>>>(conv_w, conv_b, loc_w, query, sb, W2, qb);

  dim3 grid((T_ + TT_ - 1) / TT_, B_);  // 32 x 64
  energy_kernel<<<grid, 256, 0, stream>>>(wmem, prev, qb, W2, sv, energy);

  softmax_kernel<<<B_, 256, 0, stream>>>(energy, prev, lens, out);
}